// Round 5
// baseline (537.830 us; speedup 1.0000x reference)
//
#include <hip/hip_runtime.h>
#include <hip/hip_fp16.h>

#define INVS 0.35355339059327373f  // 1/(2*sqrt(2))
#define CCH 28
#define VSTR 32                    // padded voxel stride in halves (64 B = 1 cache sector)
#define CAP 256                    // bucket capacity (mean 122, sd 11 -> 12 sigma)

typedef float f32x4 __attribute__((ext_vector_type(4)));

// 8-coeff 3D Haar butterfly. c[b], b = u*4+v*2+w; o[p*4+q*2+r].
__device__ __forceinline__ void haar8(const float c[8], float o[8]) {
    float t00p = c[0] + c[1], t00m = c[0] - c[1];
    float t01p = c[2] + c[3], t01m = c[2] - c[3];
    float t10p = c[4] + c[5], t10m = c[4] - c[5];
    float t11p = c[6] + c[7], t11m = c[6] - c[7];
    float u00p = t00p + t01p, u00m = t00m + t01m;
    float u01p = t00p - t01p, u01m = t00m - t01m;
    float u10p = t10p + t11p, u10m = t10m + t11m;
    float u11p = t10p - t11p, u11m = t10m - t11m;
    o[0] = (u00p + u10p) * INVS;  o[1] = (u00m + u10m) * INVS;
    o[2] = (u01p + u11p) * INVS;  o[3] = (u01m + u11m) * INVS;
    o[4] = (u00p - u10p) * INVS;  o[5] = (u00m - u10m) * INVS;
    o[6] = (u01p - u11p) * INVS;  o[7] = (u01m - u11m) * INVS;
}

// Pixel coords with NO fma contraction (__f*_rn): bit-identical across kernels.
__device__ __forceinline__ float3 pixcoord(float x, float y, float z) {
    const float R1 = 63.5f, IB = 1.0f / 1.5f;
    float3 p;
    p.x = __fmul_rn(__fadd_rn(__fmul_rn(x, IB), 1.0f), R1);
    p.y = __fmul_rn(__fadd_rn(__fmul_rn(y, IB), 1.0f), R1);
    p.z = __fmul_rn(__fadd_rn(__fmul_rn(z, IB), 1.0f), R1);
    return p;
}
// Cells: 8x8 in x/y, 4 in z -> 16*16*32 = 8192 cells.
__device__ __forceinline__ int cell_of(float3 p) {
    int cx = min(max((int)floorf(p.x), 0), 127) >> 3;
    int cy = min(max((int)floorf(p.y), 0), 127) >> 3;
    int cz = min(max((int)floorf(p.z), 0), 127) >> 2;
    return (cz * 16 + cy) * 16 + cx;
}

// Fused levels 0+1, high-parallelism: one thread per level-1 x-PAIR (28*16*32*32 =
// 458,752 threads = 28 waves/CU). Parent (level-0) value recomputed on the fly from
// approx+det0 (8 loads, 4x redundant across sibling threads -> L2-served). Also
// zeroes the scatter cursor (folds the memset dispatch).
__global__ void __launch_bounds__(256) idwt01(const float* __restrict__ approx,
                                              const float* __restrict__ det0,
                                              const float* __restrict__ det1,
                                              __half* __restrict__ vol1,
                                              int* __restrict__ curs) {
    constexpr int D03 = 16 * 16 * 16, D13 = 32 * 32 * 32;
    int t = blockIdx.x * 256 + threadIdx.x;    // 1792 blocks exactly
    if (t < 8192) curs[t] = 0;
    int xp = t & 15;                           // level-1 x-pair: x1 = 2xp, 2xp+1
    int y1 = (t >> 4) & 31;
    int z1 = (t >> 9) & 31;
    int c  = t >> 14;                          // 0..27 exact
    // Parent level-0 voxel (both pair members share it: x0 = xp).
    int base0 = c * D03 + (((z1 >> 1) * 16 + (y1 >> 1)) * 16 + xp);
    float cf[8];
    cf[0] = approx[base0];
#pragma unroll
    for (int j = 0; j < 7; ++j) cf[j + 1] = det0[j * (CCH * D03) + base0];
    float v0[8];
    haar8(cf, v0);
    int sub = (z1 & 1) * 4 + (y1 & 1) * 2;     // A: sub+0, B: sub+1
    // Level 1 for the two x-neighbors.
    int base1 = c * D13 + ((z1 * 32 + y1) * 32 + 2 * xp);
    float cfA[8], cfB[8];
    cfA[0] = v0[sub];
    cfB[0] = v0[sub + 1];
#pragma unroll
    for (int j = 0; j < 7; ++j) {
        float2 d2 = *(const float2*)(det1 + j * (CCH * D13) + base1);
        cfA[j + 1] = d2.x;
        cfB[j + 1] = d2.y;
    }
    float oA[8], oB[8];
    haar8(cfA, oA);
    haar8(cfB, oB);
    // Fine voxels: A -> x = 4xp+{0,1}, B -> x = 4xp+{2,3}: one uint2 per fine row.
    uint2* outv = (uint2*)vol1;
#pragma unroll
    for (int p = 0; p < 2; ++p)
#pragma unroll
        for (int q = 0; q < 2; ++q) {
            int k0 = p * 4 + q * 2;
            __half2 lo, hi;
            lo.x = __float2half(oA[k0]);     lo.y = __float2half(oA[k0 + 1]);
            hi.x = __float2half(oB[k0]);     hi.y = __float2half(oB[k0 + 1]);
            uint2 v;
            v.x = *(unsigned int*)&lo;
            v.y = *(unsigned int*)&hi;
            long oi = (((long)(c * 64 + 2 * z1 + p) * 64 + 2 * y1 + q) * 64 + 4 * xp) >> 2;
            outv[oi] = v;
        }
}

// Level 2: (28,64^3) fp16 ch-first -> (128,128,128, VSTR=32-padded ch) fp16 ch-last.
// Pads (ch 28..31) written as 0, never consumed: each voxel = one aligned 64 B sector.
__global__ void __launch_bounds__(256) idwt_last(const __half* __restrict__ vol1,
                                                 const float* __restrict__ details,
                                                 __half* __restrict__ out) {
    constexpr int D3 = 64 * 64 * 64;
    __shared__ unsigned int lds4[4 * CCH * 65];          // 29,120 B
    unsigned short* lds = (unsigned short*)lds4;         // shorts: [(m*28+c)*130 + vox]
    int zc = blockIdx.x >> 6, yc = blockIdx.x & 63;
    int rowc = (zc * 64 + yc) * 64;
    int xc = threadIdx.x & 63, cg = threadIdx.x >> 6;    // cg 0..3
#pragma unroll
    for (int k = 0; k < 7; ++k) {
        int c = cg + 4 * k;                              // covers 0..27 exactly
        int base = c * D3 + rowc + xc;
        float cf[8];
        cf[0] = (float)vol1[base];
#pragma unroll
        for (int j = 0; j < 7; ++j) cf[j + 1] = details[j * (CCH * D3) + base];
        float o[8];
        haar8(cf, o);
#pragma unroll
        for (int m = 0; m < 4; ++m) {                    // m = p*2+q
            __half2 h;
            h.x = __float2half(o[2 * m]);
            h.y = __float2half(o[2 * m + 1]);
            lds4[(m * CCH + c) * 65 + xc] = *(unsigned int*)&h;
        }
    }
    __syncthreads();
    // 4 fine rows x (128 vox * 32 padded ch = 4096 halves = 512 uint4) = 2048 chunks.
#pragma unroll
    for (int it = 0; it < 8; ++it) {
        int t2 = it * 256 + threadIdx.x;       // 0..2047
        int plane = t2 >> 9;
        int rem = t2 & 511;
        int p = plane >> 1, q = plane & 1;
        int vox = rem >> 2;
        int bc = (rem & 3) * 8;
        unsigned int h[8];
#pragma unroll
        for (int j = 0; j < 8; ++j) {
            int ch = bc + j;
            h[j] = (ch < CCH) ? (unsigned int)lds[(plane * CCH + ch) * 130 + vox] : 0u;
        }
        uint4 r4;
        r4.x = h[0] | (h[1] << 16);
        r4.y = h[2] | (h[3] << 16);
        r4.z = h[4] | (h[5] << 16);
        r4.w = h[6] | (h[7] << 16);
        long orow = ((long)(2 * zc + p) * 128 + (2 * yc + q)) * (128L * VSTR);
        ((uint4*)(out + orow))[rem] = r4;      // contiguous per wave
    }
}

// Bucket scatter: one atomicAdd per query, implicit offsets (cell*CAP). Overflow
// (>=12 sigma, impossible for ~uniform input) handled exactly via direct gather.
__global__ void scatter_k(const float* __restrict__ xyz, int* __restrict__ cursor,
                          unsigned int* __restrict__ recs, const __half* __restrict__ vol,
                          float* __restrict__ out, int N) {
    int i = blockIdx.x * 256 + threadIdx.x;
    if (i >= N) return;
    float3 p = pixcoord(xyz[3 * i], xyz[3 * i + 1], xyz[3 * i + 2]);
    int cell = cell_of(p);
    int pos = atomicAdd(&cursor[cell], 1);
    if (pos < CAP) {
        recs[cell * CAP + pos] = (unsigned int)i;
        return;
    }
    // Slow path: direct global gather (padded channel-last, 64 B/voxel).
    float flx = floorf(p.x), fly = floorf(p.y), flz = floorf(p.z);
    int ix0 = (int)flx, iy0 = (int)fly, iz0 = (int)flz;
    float fx = p.x - flx, fy = p.y - fly, fz = p.z - flz;
    float acc[CCH];
#pragma unroll
    for (int k = 0; k < CCH; ++k) acc[k] = 0.0f;
    for (int dz = 0; dz < 2; ++dz) {
        int iz = iz0 + dz;
        bool vz = (iz >= 0) & (iz < 128);
        float wz = dz ? fz : 1.0f - fz;
        int gz = min(max(iz, 0), 127);
        for (int dy = 0; dy < 2; ++dy) {
            int iy = iy0 + dy;
            bool vy = (iy >= 0) & (iy < 128);
            float wy = dy ? fy : 1.0f - fy;
            int gy = min(max(iy, 0), 127);
            for (int dx = 0; dx < 2; ++dx) {
                int ix = ix0 + dx;
                bool vx = (ix >= 0) & (ix < 128);
                float wx = dx ? fx : 1.0f - fx;
                int gx = min(max(ix, 0), 127);
                float w = (vx & vy & vz) ? (wx * wy * wz) : 0.0f;
                const uint2* pv = (const uint2*)(vol + (((long)(gz * 128 + gy) * 128 + gx) << 5));
#pragma unroll
                for (int j = 0; j < 7; ++j) {
                    uint2 u = pv[j];
                    float2 f0 = __half22float2(*(__half2*)&u.x);
                    float2 f1 = __half22float2(*(__half2*)&u.y);
                    acc[4 * j + 0] += w * f0.x;
                    acc[4 * j + 1] += w * f0.y;
                    acc[4 * j + 2] += w * f1.x;
                    acc[4 * j + 3] += w * f1.y;
                }
            }
        }
    }
#pragma unroll
    for (int k = 0; k < CCH; ++k) out[(long)i * CCH + k] = acc[k];
}

// acc[0..27] += w * (14 half2 dwords; a3.zw are pad)
__device__ __forceinline__ void fma14(float acc[CCH], uint4 a0, uint4 a1, uint4 a2, uint4 a3,
                                      float w) {
    unsigned int u[14] = {a0.x, a0.y, a0.z, a0.w, a1.x, a1.y, a1.z, a1.w,
                          a2.x, a2.y, a2.z, a2.w, a3.x, a3.y};
#pragma unroll
    for (int d = 0; d < 14; ++d) {
        float2 f = __half22float2(*(__half2*)&u[d]);
        acc[2 * d]     += w * f.x;
        acc[2 * d + 1] += w * f.y;
    }
}

// One block per cell; thread k serves query k. No LDS, no barrier: direct gathers.
// Cell-sorted order keeps each block's 23 KB region L2-resident (R2's failure was
// random order over 134 MB, not the gather itself). Each corner = 4 aligned 16B loads.
__global__ void __launch_bounds__(256) query_cell(const unsigned int* __restrict__ recs,
                                                  const int* __restrict__ cursor,
                                                  const float* __restrict__ xyz,
                                                  const __half* __restrict__ vol,
                                                  float* __restrict__ out) {
    int cell = blockIdx.x;
    int k = threadIdx.x;
    int cnt = min(cursor[cell], CAP);
    if (k >= cnt) return;                      // fast-exit waves free their slots
    int q = (int)recs[cell * CAP + k];
    float3 p = pixcoord(xyz[3 * q], xyz[3 * q + 1], xyz[3 * q + 2]);
    float flx = floorf(p.x), fly = floorf(p.y), flz = floorf(p.z);
    int ix0 = (int)flx, iy0 = (int)fly, iz0 = (int)flz;
    float fx = p.x - flx, fy = p.y - fly, fz = p.z - flz;
    // Per-axis clamped index + validity-zeroed weight (product == corner validity).
    int gx0 = min(max(ix0, 0), 127),     gy0 = min(max(iy0, 0), 127),     gz0 = min(max(iz0, 0), 127);
    int gx1 = min(max(ix0 + 1, 0), 127), gy1 = min(max(iy0 + 1, 0), 127), gz1 = min(max(iz0 + 1, 0), 127);
    float wx0 = (ix0 >= 0 && ix0 < 128) ? 1.0f - fx : 0.0f;
    float wx1 = (ix0 + 1 >= 0 && ix0 + 1 < 128) ? fx : 0.0f;
    float wy0 = (iy0 >= 0 && iy0 < 128) ? 1.0f - fy : 0.0f;
    float wy1 = (iy0 + 1 >= 0 && iy0 + 1 < 128) ? fy : 0.0f;
    float wz0 = (iz0 >= 0 && iz0 < 128) ? 1.0f - fz : 0.0f;
    float wz1 = (iz0 + 1 >= 0 && iz0 + 1 < 128) ? fz : 0.0f;

    float acc[CCH];
#pragma unroll
    for (int j = 0; j < CCH; ++j) acc[j] = 0.0f;
#pragma unroll
    for (int c8 = 0; c8 < 8; ++c8) {
        int gx = (c8 & 1) ? gx1 : gx0;
        int gy = (c8 & 2) ? gy1 : gy0;
        int gz = (c8 & 4) ? gz1 : gz0;
        float w = ((c8 & 1) ? wx1 : wx0) * ((c8 & 2) ? wy1 : wy0) * ((c8 & 4) ? wz1 : wz0);
        const uint4* pv = (const uint4*)(vol + (((long)(gz * 128 + gy) * 128 + gx) << 5));
        uint4 a0 = pv[0], a1 = pv[1], a2 = pv[2], a3 = pv[3];
        fma14(acc, a0, a1, a2, a3, w);
    }
    f32x4* o4 = (f32x4*)(out + (long)q * CCH);  // 112B rows, 16B aligned
#pragma unroll
    for (int j = 0; j < 7; ++j) {
        f32x4 v = {acc[4 * j], acc[4 * j + 1], acc[4 * j + 2], acc[4 * j + 3]};
        o4[j] = v;                             // plain stores: L2 write-combines
    }
}

extern "C" void kernel_launch(void* const* d_in, const int* in_sizes, int n_in,
                              void* d_out, int out_size, void* d_ws, size_t ws_size,
                              hipStream_t stream) {
    const float* approx = (const float*)d_in[0];   // (28,16,16,16)
    const float* det0   = (const float*)d_in[1];   // (7,28,16,16,16)
    const float* det1   = (const float*)d_in[2];   // (7,28,32,32,32)
    const float* det2   = (const float*)d_in[3];   // (7,28,64,64,64)
    const float* xyz    = (const float*)d_in[4];   // (N,3)
    int N = in_sizes[4] / 3;

    char* ws = (char*)d_ws;
    // vol1  @0          : 14,680,064  (28*64^3 fp16, ch-first; dead after idwt_last)
    // recs  @0          : 8,388,608   (8192*256*4B) -- aliases dead vol1 (scatter
    //                     runs strictly after idwt_last on the stream)
    // vol2p @14,680,064 : 134,217,728 (128^3 * 32-padded ch fp16, channel-last)
    // curs  @148,897,792: 32,768      -> total 148,930,560 B (< proven 150,004,752)
    __half*       vol1  = (__half*)ws;
    unsigned int* recs  = (unsigned int*)ws;
    __half*       vol2  = (__half*)(ws + 14680064);
    int*          curs  = (int*)(ws + 148897792);

    idwt01<<<1792, 256, 0, stream>>>(approx, det0, det1, vol1, curs);
    idwt_last<<<4096, 256, 0, stream>>>(vol1, det2, vol2);
    int nb = (N + 255) / 256;
    scatter_k<<<nb, 256, 0, stream>>>(xyz, curs, recs, vol2, (float*)d_out, N);
    query_cell<<<8192, 256, 0, stream>>>(recs, curs, xyz, vol2, (float*)d_out);
}